// Round 2
// baseline (1859.095 us; speedup 1.0000x reference)
//
#include <hip/hip_runtime.h>
#include <math.h>

typedef __bf16 bf16_t;
typedef bf16_t bf16x8 __attribute__((ext_vector_type(8)));
typedef float f32x4 __attribute__((ext_vector_type(4)));

#define TOKS 73728
#define CCH 192

__device__ __forceinline__ float gelu_f(float x) {
  float t = tanhf(0.7978845608028654f*(x + 0.044715f*x*x*x));
  return 0.5f*x*(1.0f + t);
}

__device__ __forceinline__ void glds16(const void* g, void* l) {
  __builtin_amdgcn_global_load_lds(
      (const __attribute__((address_space(1))) void*)g,
      (__attribute__((address_space(3))) void*)l, 16, 0, 0);
}

// ---------- weight prep: f32 [cnt][K][N] -> bf16 [cnt][N][K] ----------
__global__ void wprep_k(const float* __restrict__ in, bf16_t* __restrict__ out,
                        int K, int N, long total) {
  long idx = (long)blockIdx.x*256 + threadIdx.x;
  if (idx >= total) return;
  long kn = (long)K*N;
  long c = idx / kn;
  int rem = (int)(idx - c*kn);
  int k = rem / N, n = rem % N;
  out[c*kn + (long)n*K + k] = (bf16_t)in[idx];
}

// conv_w (192,192,3,3) f32 -> bf16 [tap][co][ci]
__global__ void cprep_k(const float* __restrict__ in, bf16_t* __restrict__ out) {
  int idx = blockIdx.x*256 + threadIdx.x;
  if (idx >= 9*192*192) return;
  int tap = idx / (192*192);
  int co = (idx / 192) % 192;
  int ci = idx % 192;
  out[idx] = (bf16_t)in[(co*192 + ci)*9 + tap];
}

// ---------- LayerNorm: f32 x (T,192) -> bf16 out ----------
__global__ __launch_bounds__(256) void ln_k(const float* __restrict__ x,
    const float* __restrict__ gg, const float* __restrict__ bb,
    bf16_t* __restrict__ out) {
  const int wid = blockIdx.x*4 + (threadIdx.x >> 6);
  const int l = threadIdx.x & 63;
  const float* row = x + (long)wid*CCH;
  float v0 = row[l], v1 = row[l+64], v2 = row[l+128];
  float s = v0+v1+v2, s2 = v0*v0+v1*v1+v2*v2;
  #pragma unroll
  for (int off=1; off<64; off<<=1) { s += __shfl_xor(s, off); s2 += __shfl_xor(s2, off); }
  float mu = s * (1.f/CCH);
  float rstd = rsqrtf(s2*(1.f/CCH) - mu*mu + 1e-5f);
  bf16_t* orow = out + (long)wid*CCH;
  orow[l]     = (bf16_t)((v0-mu)*rstd*gg[l]     + bb[l]);
  orow[l+64]  = (bf16_t)((v1-mu)*rstd*gg[l+64]  + bb[l+64]);
  orow[l+128] = (bf16_t)((v2-mu)*rstd*gg[l+128] + bb[l+128]);
}

// ---------- GEMM v2: 128x64 tile, BK=32, dbuf LDS via global_load_lds ----------
// C(M,N) = A(M,K) @ Bt(N,K)^T + bias
// EPI 0: bf16 store; 1: gelu->bf16; 2: resid += v; 3: residb = bf16(resid+v)
template<int EPI>
__global__ __launch_bounds__(256) void gemm2_k(
    const bf16_t* __restrict__ A, int lda,
    const bf16_t* __restrict__ Bt,
    const float* __restrict__ bias,
    bf16_t* __restrict__ outb, int ldo, int ooff,
    float* __restrict__ resid, bf16_t* __restrict__ residb,
    int N, int K) {
  __shared__ bf16_t As[2][4096];   // 128 rows x 32 (64B rows)
  __shared__ bf16_t Bs[2][2048];   // 64 rows x 32
  const int tid = threadIdx.x;
  const int w = tid >> 6, l = tid & 63;
  const int lr = l & 15, lk = l >> 4;
  const int rq = l >> 2, cq = (l & 3) * 8;
  const long m0 = (long)blockIdx.x * 128;
  const int n0 = blockIdx.y * 64;

  f32x4 acc[2][4];
  #pragma unroll
  for (int mi=0; mi<2; ++mi)
    #pragma unroll
    for (int ni=0; ni<4; ++ni) acc[mi][ni] = (f32x4){0.f,0.f,0.f,0.f};

  const int nk = K >> 5;
  auto stage = [&](int buf, int k0) {
    #pragma unroll
    for (int j = 0; j < 2; ++j) {
      const int s = w*2 + j;
      const bf16_t* asrc = A + (m0 + s*16 + rq)*(long)lda + k0 + cq;
      glds16(asrc, &As[buf][s*512]);
    }
    const bf16_t* bsrc = Bt + (long)(n0 + w*16 + rq)*K + k0 + cq;
    glds16(bsrc, &Bs[buf][w*512]);
  };

  stage(0, 0);
  __syncthreads();
  for (int kt = 0; kt < nk; ++kt) {
    const int cur = kt & 1;
    if (kt + 1 < nk) stage(cur^1, (kt+1)*32);
    bf16x8 af[2], bfr[4];
    #pragma unroll
    for (int mi=0; mi<2; ++mi)
      af[mi] = *(const bf16x8*)(&As[cur][(w*32 + mi*16 + lr)*32 + lk*8]);
    #pragma unroll
    for (int ni=0; ni<4; ++ni)
      bfr[ni] = *(const bf16x8*)(&Bs[cur][(ni*16 + lr)*32 + lk*8]);
    #pragma unroll
    for (int mi=0; mi<2; ++mi)
      #pragma unroll
      for (int ni=0; ni<4; ++ni)
        acc[mi][ni] = __builtin_amdgcn_mfma_f32_16x16x32_bf16(af[mi], bfr[ni], acc[mi][ni], 0, 0, 0);
    __syncthreads();
  }

  #pragma unroll
  for (int mi=0; mi<2; ++mi) {
    const long r0 = m0 + w*32 + mi*16 + lk*4;
    #pragma unroll
    for (int ni=0; ni<4; ++ni) {
      const int col = n0 + ni*16 + lr;
      if (col >= N) continue;
      const float bsv = bias[col];
      #pragma unroll
      for (int e=0; e<4; ++e) {
        const long row = r0 + e;
        const float v = acc[mi][ni][e] + bsv;
        if (EPI == 0)      outb[row*ldo + ooff + col] = (bf16_t)v;
        else if (EPI == 1) outb[row*ldo + ooff + col] = (bf16_t)gelu_f(v);
        else if (EPI == 2) resid[row*CCH + col] += v;
        else {
          float r = resid[row*CCH + col] + v;
          resid[row*CCH + col] = r;
          residb[row*CCH + col] = (bf16_t)r;
        }
      }
    }
  }
}

// ---------- window attention (1 block = 1 window, 1 wave = 1 head) ----------
__global__ __launch_bounds__(256) void win_attn_k(
    const bf16_t* __restrict__ qkv, bf16_t* __restrict__ aout,
    const float* __restrict__ rpb, int shift) {
  __shared__ float Ks[4][64][24];
  __shared__ float Vs[4][64][24];
  const int h = threadIdx.x >> 6, l = threadIdx.x & 63;
  const int wblk = blockIdx.x;
  const int b = wblk / 576, wi = wblk % 576;
  const int wh = wi / 24, ww = wi % 24;
  const int r = l >> 3, c = l & 7;
  const int hr = wh*8 + r, wr = ww*8 + c;
  int ho = hr + shift; if (ho >= 192) ho -= 192;
  int wo = wr + shift; if (wo >= 192) wo -= 192;
  const long tok = (long)b*36864 + (long)ho*192 + wo;
  const bf16_t* base = qkv + tok*576 + h*24;
  float q[24];
  #pragma unroll
  for (int j=0; j<3; ++j) {
    bf16x8 qv8 = *(const bf16x8*)(base + j*8);
    bf16x8 kv8 = *(const bf16x8*)(base + 96 + j*8);
    bf16x8 vv8 = *(const bf16x8*)(base + 192 + j*8);
    #pragma unroll
    for (int e=0; e<8; ++e) {
      q[j*8+e] = (float)qv8[e];
      Ks[h][l][j*8+e] = (float)kv8[e];
      Vs[h][l][j*8+e] = (float)vv8[e];
    }
  }
  __syncthreads();
  int qid = 0;
  if (shift) {
    int hid = (hr < 184) ? 0 : (hr < 188 ? 1 : 2);
    int wid2 = (wr < 184) ? 0 : (wr < 188 ? 1 : 2);
    qid = hid*3 + wid2;
  }
  const float scale = 0.20412414523193154f;
  float lg[64];
  #pragma unroll
  for (int m=0; m<64; ++m) {
    int r2 = m >> 3, c2 = m & 7;
    float dot = 0.f;
    #pragma unroll
    for (int d4=0; d4<6; ++d4) {
      float4 kv = *(const float4*)(&Ks[h][m][d4*4]);
      dot += q[d4*4+0]*kv.x + q[d4*4+1]*kv.y + q[d4*4+2]*kv.z + q[d4*4+3]*kv.w;
    }
    int ridx = (r - r2 + 7)*15 + (c - c2 + 7);
    float v = dot*scale + rpb[ridx*4 + h];
    if (shift) {
      int hr2 = wh*8 + r2, wr2 = ww*8 + c2;
      int hid2 = (hr2 < 184) ? 0 : (hr2 < 188 ? 1 : 2);
      int wid3 = (wr2 < 184) ? 0 : (wr2 < 188 ? 1 : 2);
      if (hid2*3 + wid3 != qid) v -= 100.f;
    }
    lg[m] = v;
  }
  float mx = -1e30f;
  #pragma unroll
  for (int m=0; m<64; ++m) mx = fmaxf(mx, lg[m]);
  float s = 0.f;
  float o[24];
  #pragma unroll
  for (int d=0; d<24; ++d) o[d] = 0.f;
  #pragma unroll
  for (int m=0; m<64; ++m) {
    float p = __expf(lg[m] - mx);
    s += p;
    #pragma unroll
    for (int d4=0; d4<6; ++d4) {
      float4 vv = *(const float4*)(&Vs[h][m][d4*4]);
      o[d4*4+0] += p*vv.x; o[d4*4+1] += p*vv.y; o[d4*4+2] += p*vv.z; o[d4*4+3] += p*vv.w;
    }
  }
  float inv = 1.f/s;
  bf16_t* ob = aout + tok*192 + h*24;
  #pragma unroll
  for (int j=0; j<3; ++j) {
    bf16x8 ov;
    #pragma unroll
    for (int e=0; e<8; ++e) ov[e] = (bf16_t)(o[j*8+e]*inv);
    *(bf16x8*)(ob + j*8) = ov;
  }
}

// ---------- anchored stripe attention ----------
__global__ __launch_bounds__(256) void stripe_attn_k(
    const bf16_t* __restrict__ qkv, const bf16_t* __restrict__ xn,
    bf16_t* __restrict__ aout) {
  __shared__ float Ks[4][64][24];
  __shared__ float Vs[4][64][24];
  __shared__ float An[4][16][24];
  __shared__ float Ts[4][16][24];
  const int h = threadIdx.x >> 6, l = threadIdx.x & 63;
  const int wblk = blockIdx.x;
  const int b = wblk / 576, wi = wblk % 576;
  const int wh = wi / 24, ww = wi % 24;
  const int r = l >> 3, c = l & 7;
  const long tok = (long)b*36864 + (long)(wh*8+r)*192 + (ww*8+c);
  const bf16_t* base = qkv + tok*576 + 288 + h*24;
  #pragma unroll
  for (int j=0; j<3; ++j) {
    bf16x8 kv8 = *(const bf16x8*)(base + 96 + j*8);
    bf16x8 vv8 = *(const bf16x8*)(base + 192 + j*8);
    #pragma unroll
    for (int e=0; e<8; ++e) {
      Ks[h][l][j*8+e] = (float)kv8[e];
      Vs[h][l][j*8+e] = (float)vv8[e];
    }
  }
  {
    int m = l >> 2, dq = l & 3;
    int ar = m >> 2, ac = m & 3;
    const long trow = (long)b*36864 + (long)(wh*8 + 2*ar)*192 + (ww*8 + 2*ac);
    #pragma unroll
    for (int j=0; j<6; ++j) {
      int d = dq*6 + j;
      float ssum = 0.f;
      ssum += (float)xn[trow*192       + 96 + h*24 + d];
      ssum += (float)xn[(trow+1)*192   + 96 + h*24 + d];
      ssum += (float)xn[(trow+192)*192 + 96 + h*24 + d];
      ssum += (float)xn[(trow+193)*192 + 96 + h*24 + d];
      An[h][m][d] = 0.25f*ssum;
    }
  }
  __syncthreads();
  const float scale = 0.20412414523193154f;
  {
    int g = l >> 2, qq = l & 3;
    float l2[16];
    #pragma unroll
    for (int t=0; t<16; ++t) {
      int k = qq*16 + t;
      float dot = 0.f;
      #pragma unroll
      for (int d4=0; d4<6; ++d4) {
        float4 av = *(const float4*)(&An[h][g][d4*4]);
        float4 kv = *(const float4*)(&Ks[h][k][d4*4]);
        dot += av.x*kv.x + av.y*kv.y + av.z*kv.z + av.w*kv.w;
      }
      l2[t] = dot*scale;
    }
    float mx = -1e30f;
    #pragma unroll
    for (int t=0; t<16; ++t) mx = fmaxf(mx, l2[t]);
    mx = fmaxf(mx, __shfl_xor(mx, 1));
    mx = fmaxf(mx, __shfl_xor(mx, 2));
    float ssum = 0.f;
    float p[16];
    #pragma unroll
    for (int t=0; t<16; ++t) { p[t] = __expf(l2[t]-mx); ssum += p[t]; }
    ssum += __shfl_xor(ssum, 1);
    ssum += __shfl_xor(ssum, 2);
    float ta[24];
    #pragma unroll
    for (int d=0; d<24; ++d) ta[d] = 0.f;
    #pragma unroll
    for (int t=0; t<16; ++t) {
      int k = qq*16 + t;
      #pragma unroll
      for (int d4=0; d4<6; ++d4) {
        float4 vv = *(const float4*)(&Vs[h][k][d4*4]);
        ta[d4*4+0] += p[t]*vv.x; ta[d4*4+1] += p[t]*vv.y;
        ta[d4*4+2] += p[t]*vv.z; ta[d4*4+3] += p[t]*vv.w;
      }
    }
    #pragma unroll
    for (int d=0; d<24; ++d) {
      ta[d] += __shfl_xor(ta[d], 1);
      ta[d] += __shfl_xor(ta[d], 2);
    }
    float inv = 1.f/ssum;
    #pragma unroll
    for (int j=0; j<6; ++j) Ts[h][g][qq*6+j] = ta[qq*6+j]*inv;
  }
  __syncthreads();
  {
    float qv[24];
    #pragma unroll
    for (int j=0; j<3; ++j) {
      bf16x8 q8 = *(const bf16x8*)(base + j*8);
      #pragma unroll
      for (int e=0; e<8; ++e) qv[j*8+e] = (float)q8[e];
    }
    float lg[16];
    #pragma unroll
    for (int m=0; m<16; ++m) {
      float dot = 0.f;
      #pragma unroll
      for (int d4=0; d4<6; ++d4) {
        float4 av = *(const float4*)(&An[h][m][d4*4]);
        dot += qv[d4*4+0]*av.x + qv[d4*4+1]*av.y + qv[d4*4+2]*av.z + qv[d4*4+3]*av.w;
      }
      lg[m] = dot*scale;
    }
    float mx = -1e30f;
    #pragma unroll
    for (int m=0; m<16; ++m) mx = fmaxf(mx, lg[m]);
    float s = 0.f;
    float o[24];
    #pragma unroll
    for (int d=0; d<24; ++d) o[d] = 0.f;
    #pragma unroll
    for (int m=0; m<16; ++m) {
      float p = __expf(lg[m]-mx);
      s += p;
      #pragma unroll
      for (int d4=0; d4<6; ++d4) {
        float4 tv = *(const float4*)(&Ts[h][m][d4*4]);
        o[d4*4+0] += p*tv.x; o[d4*4+1] += p*tv.y; o[d4*4+2] += p*tv.z; o[d4*4+3] += p*tv.w;
      }
    }
    float inv = 1.f/s;
    bf16_t* ob = aout + tok*192 + 96 + h*24;
    #pragma unroll
    for (int j=0; j<3; ++j) {
      bf16x8 ov;
      #pragma unroll
      for (int e=0; e<8; ++e) ov[e] = (bf16_t)(o[j*8+e]*inv);
      *(bf16x8*)(ob + j*8) = ov;
    }
  }
}

// ---------- conv v2: block = 1 image row (192 tok) x 96 co ----------
// LDS: 3-row x-halo per 32-ch chunk (reused by all 9 taps) + per-tap W tiles
__global__ __launch_bounds__(256) void conv2_k(
    const bf16_t* __restrict__ xb,   // [2][192][192][192] bf16
    const bf16_t* __restrict__ Wc,   // [9][192][192] bf16
    const float* __restrict__ cb,
    const float* __restrict__ res0,
    const bf16_t* __restrict__ zb,   // >=1KB of zeros
    float* __restrict__ out) {
  __shared__ bf16_t Xs[19968];   // [3 dy][208 tok][32 ch] (64B per tok) = 39,936B
  __shared__ bf16_t Bs[27648];   // [9 tap][96 co][32 ch] = 55,296B
  const int tid = threadIdx.x;
  const int w = tid >> 6, l = tid & 63;
  const int lr = l & 15, lk = l >> 4;
  const int rq = l >> 2, cq = (l & 3) * 8;
  const int bx = blockIdx.x;
  const int bimg = bx / 192, h = bx % 192;
  const int co0 = blockIdx.y * 96;

  f32x4 acc[3][6];
  #pragma unroll
  for (int mi=0; mi<3; ++mi)
    #pragma unroll
    for (int ni=0; ni<6; ++ni) acc[mi][ni] = (f32x4){0.f,0.f,0.f,0.f};

  for (int kcs = 0; kcs < 6; ++kcs) {
    const int kc = kcs * 32;
    // stage X halo: 39 slots of 1KB
    for (int s = w; s < 39; s += 4) {
      int dy = s / 13, rem = s - dy*13;
      int tokcol = rem*16 + rq;     // 0..207
      int wc = tokcol - 1;
      int hp = h + dy - 1;
      const bf16_t* src = zb + cq;
      if (hp >= 0 && hp < 192 && wc >= 0 && wc < 192)
        src = xb + ((long)bimg*36864 + (long)hp*192 + wc)*192 + kc + cq;
      glds16(src, &Xs[s*512]);
    }
    // stage B: 54 slots
    for (int s = w; s < 54; s += 4) {
      int tap = s / 6, rem = s - tap*6;
      int row = rem*16 + rq;
      const bf16_t* src = Wc + ((long)(tap*192 + co0 + row))*192 + kc + cq;
      glds16(src, &Bs[s*512]);
    }
    __syncthreads();
    #pragma unroll
    for (int tap = 0; tap < 9; ++tap) {
      const int dy = tap/3, dx = tap%3 - 1;
      bf16x8 af[3];
      #pragma unroll
      for (int mi=0; mi<3; ++mi) {
        int tokcol = w*48 + mi*16 + lr + dx + 1;
        af[mi] = *(const bf16x8*)(&Xs[dy*6656 + tokcol*32 + lk*8]);
      }
      #pragma unroll
      for (int ni=0; ni<6; ++ni) {
        bf16x8 bfr = *(const bf16x8*)(&Bs[tap*3072 + (ni*16+lr)*32 + lk*8]);
        #pragma unroll
        for (int mi=0; mi<3; ++mi)
          acc[mi][ni] = __builtin_amdgcn_mfma_f32_16x16x32_bf16(af[mi], bfr, acc[mi][ni], 0, 0, 0);
      }
    }
    if (kcs < 5) __syncthreads();
  }

  #pragma unroll
  for (int mi=0; mi<3; ++mi) {
    #pragma unroll
    for (int ni=0; ni<6; ++ni) {
      const int col = co0 + ni*16 + lr;
      const float cbv = cb[col];
      #pragma unroll
      for (int e=0; e<4; ++e) {
        const int tl = w*48 + mi*16 + lk*4 + e;
        const long tok = (long)bimg*36864 + (long)h*192 + tl;
        out[tok*192 + col] = acc[mi][ni][e] + cbv + res0[tok*192 + col];
      }
    }
  }
}

extern "C" void kernel_launch(void* const* d_in, const int* in_sizes, int n_in,
                              void* d_out, int out_size, void* d_ws, size_t ws_size,
                              hipStream_t stream) {
  const float* x_in     = (const float*)d_in[0];
  const float* norm1_g  = (const float*)d_in[1];
  const float* norm1_b  = (const float*)d_in[2];
  const float* qkv_w_w  = (const float*)d_in[3];
  const float* qkv_b_w  = (const float*)d_in[4];
  const float* qkv_w_s  = (const float*)d_in[5];
  const float* qkv_b_s  = (const float*)d_in[6];
  const float* proj_w   = (const float*)d_in[7];
  const float* proj_b   = (const float*)d_in[8];
  const float* rpb      = (const float*)d_in[9];
  const float* norm2_g  = (const float*)d_in[10];
  const float* norm2_b  = (const float*)d_in[11];
  const float* fc1_w    = (const float*)d_in[12];
  const float* fc1_b    = (const float*)d_in[13];
  const float* fc2_w    = (const float*)d_in[14];
  const float* fc2_b    = (const float*)d_in[15];
  const float* conv_w   = (const float*)d_in[16];
  const float* conv_b   = (const float*)d_in[17];

  char* ws = (char*)d_ws;
  float*  x_cur = (float*)ws;                         // 56,623,104 B
  bf16_t* xn    = (bf16_t*)(ws + 56623104);           // 28,311,552 B
  bf16_t* qh    = (bf16_t*)(ws + 84934656);           // 113,246,208 B
  bf16_t* aoutb = (bf16_t*)(ws + 198180864);          // 28,311,552 B (also final-x bf16)
  bf16_t* WwinT = (bf16_t*)(ws + 226492416);
  bf16_t* WstrT  = WwinT  + 110592;
  bf16_t* WprojT = WstrT  + 110592;
  bf16_t* Wfc1T  = WprojT + 147456;
  bf16_t* Wfc2T  = Wfc1T  + 589824;
  bf16_t* WconvT = Wfc2T  + 589824;

  hipMemcpyAsync(x_cur, x_in, (size_t)TOKS*CCH*4, hipMemcpyDeviceToDevice, stream);

  wprep_k<<<(4*96*288 + 255)/256, 256, 0, stream>>>(qkv_w_w, WwinT, 96, 288, 4L*96*288);
  wprep_k<<<(4*96*288 + 255)/256, 256, 0, stream>>>(qkv_w_s, WstrT, 96, 288, 4L*96*288);
  wprep_k<<<(4*192*192 + 255)/256, 256, 0, stream>>>(proj_w, WprojT, 192, 192, 4L*192*192);
  wprep_k<<<(4*192*768 + 255)/256, 256, 0, stream>>>(fc1_w, Wfc1T, 192, 768, 4L*192*768);
  wprep_k<<<(4*768*192 + 255)/256, 256, 0, stream>>>(fc2_w, Wfc2T, 768, 192, 4L*768*192);
  cprep_k<<<(9*192*192 + 255)/256, 256, 0, stream>>>(conv_w, WconvT);

  const int MB = TOKS/128;  // 576
  for (int i = 0; i < 4; ++i) {
    int shift = (i % 2 == 0) ? 4 : 0;
    ln_k<<<TOKS/4, 256, 0, stream>>>(x_cur, norm1_g + i*192, norm1_b + i*192, xn);
    dim3 g5(MB, 5), g3(MB, 3), g12(MB, 12);
    gemm2_k<0><<<g5, 256, 0, stream>>>(xn,      192, WwinT + (long)i*27648, qkv_b_w + i*288,
                                       qh, 576, 0,   nullptr, nullptr, 288, 96);
    gemm2_k<0><<<g5, 256, 0, stream>>>(xn + 96, 192, WstrT + (long)i*27648, qkv_b_s + i*288,
                                       qh, 576, 288, nullptr, nullptr, 288, 96);
    win_attn_k<<<1152, 256, 0, stream>>>(qh, aoutb, rpb + i*900, shift);
    stripe_attn_k<<<1152, 256, 0, stream>>>(qh, xn, aoutb);
    gemm2_k<2><<<g3, 256, 0, stream>>>(aoutb, 192, WprojT + (long)i*36864, proj_b + i*192,
                                       nullptr, 0, 0, x_cur, nullptr, 192, 192);
    ln_k<<<TOKS/4, 256, 0, stream>>>(x_cur, norm2_g + i*192, norm2_b + i*192, xn);
    gemm2_k<1><<<g12, 256, 0, stream>>>(xn, 192, Wfc1T + (long)i*147456, fc1_b + i*768,
                                        qh, 768, 0, nullptr, nullptr, 768, 192);
    if (i < 3)
      gemm2_k<2><<<g3, 256, 0, stream>>>(qh, 768, Wfc2T + (long)i*147456, fc2_b + i*192,
                                         nullptr, 0, 0, x_cur, nullptr, 192, 768);
    else
      gemm2_k<3><<<g3, 256, 0, stream>>>(qh, 768, Wfc2T + (long)i*147456, fc2_b + i*192,
                                         nullptr, 0, 0, x_cur, aoutb, 192, 768);
  }
  // zero scratch for conv padding reads (qh is free now)
  hipMemsetAsync(qh, 0, 4096, stream);
  dim3 gc(384, 2);
  conv2_k<<<gc, 256, 0, stream>>>(aoutb, WconvT, conv_b, x_in, qh, (float*)d_out);
}

// Round 3
// 1819.302 us; speedup vs baseline: 1.0219x; 1.0219x over previous
//
#include <hip/hip_runtime.h>
#include <math.h>

typedef __bf16 bf16_t;
typedef bf16_t bf16x8 __attribute__((ext_vector_type(8)));
typedef float f32x4 __attribute__((ext_vector_type(4)));

#define TOKS 73728
#define CCH 192

__device__ __forceinline__ float gelu_f(float x) {
  float t = tanhf(0.7978845608028654f*(x + 0.044715f*x*x*x));
  return 0.5f*x*(1.0f + t);
}

__device__ __forceinline__ void glds16(const void* g, void* l) {
  __builtin_amdgcn_global_load_lds(
      (const __attribute__((address_space(1))) void*)g,
      (__attribute__((address_space(3))) void*)l, 16, 0, 0);
}

// ---------- weight prep: f32 [cnt][K][N] -> bf16 [cnt][N][K] ----------
__global__ void wprep_k(const float* __restrict__ in, bf16_t* __restrict__ out,
                        int K, int N, long total) {
  long idx = (long)blockIdx.x*256 + threadIdx.x;
  if (idx >= total) return;
  long kn = (long)K*N;
  long c = idx / kn;
  int rem = (int)(idx - c*kn);
  int k = rem / N, n = rem % N;
  out[c*kn + (long)n*K + k] = (bf16_t)in[idx];
}

// conv_w (192,192,3,3) f32 -> bf16 [tap][co][ci]
__global__ void cprep_k(const float* __restrict__ in, bf16_t* __restrict__ out) {
  int idx = blockIdx.x*256 + threadIdx.x;
  if (idx >= 9*192*192) return;
  int tap = idx / (192*192);
  int co = (idx / 192) % 192;
  int ci = idx % 192;
  out[idx] = (bf16_t)in[(co*192 + ci)*9 + tap];
}

// ---------- LN0: x f32 -> xn bf16, and copy x -> x_cur ----------
__global__ __launch_bounds__(256) void ln0_k(const float* __restrict__ x,
    const float* __restrict__ gg, const float* __restrict__ bb,
    bf16_t* __restrict__ out, float* __restrict__ xcopy) {
  const int wid = blockIdx.x*4 + (threadIdx.x >> 6);
  const int l = threadIdx.x & 63;
  const float* row = x + (long)wid*CCH;
  float v0 = row[l], v1 = row[l+64], v2 = row[l+128];
  float s = v0+v1+v2, s2 = v0*v0+v1*v1+v2*v2;
  #pragma unroll
  for (int off=1; off<64; off<<=1) { s += __shfl_xor(s, off); s2 += __shfl_xor(s2, off); }
  float mu = s * (1.f/CCH);
  float rstd = rsqrtf(s2*(1.f/CCH) - mu*mu + 1e-5f);
  float* crow = xcopy + (long)wid*CCH;
  crow[l] = v0; crow[l+64] = v1; crow[l+128] = v2;
  bf16_t* orow = out + (long)wid*CCH;
  orow[l]     = (bf16_t)((v0-mu)*rstd*gg[l]     + bb[l]);
  orow[l+64]  = (bf16_t)((v1-mu)*rstd*gg[l+64]  + bb[l+64]);
  orow[l+128] = (bf16_t)((v2-mu)*rstd*gg[l+128] + bb[l+128]);
}

// ---------- GEMM-A: BM=128, BN=96, templated BK, swizzled LDS ----------
// EPI 0: bf16 store; 1: gelu -> bf16
template<int BK, int EPI>
__global__ __launch_bounds__(256) void gemma_k(
    const bf16_t* __restrict__ A, int lda,
    const bf16_t* __restrict__ Bt,
    const float* __restrict__ bias,
    bf16_t* __restrict__ outb, int ldo, int ooff, int K) {
  constexpr int NSLOT = BK/8;       // 16B slots per LDS row
  constexpr int MASK  = NSLOT-1;
  constexpr int KS    = BK/32;
  constexpr int RPS   = 512/BK;     // rows per 1KB wave slot
  constexpr int SLA   = 128*BK/512;
  constexpr int SLB   = 96*BK/512;
  __shared__ bf16_t As[2][128*BK];
  __shared__ bf16_t Bs[2][96*BK];
  const int tid = threadIdx.x;
  const int w = tid >> 6, l = tid & 63;
  const int lr = l & 15, lk = l >> 4;
  const int ri = l / NSLOT, si = l & MASK;
  const long m0 = (long)blockIdx.x * 128;
  const int n0 = blockIdx.y * 96;
  const int wm = w >> 1, wn = w & 1;

  f32x4 acc[4][3];
  #pragma unroll
  for (int mi=0;mi<4;++mi)
    #pragma unroll
    for (int ni=0;ni<3;++ni) acc[mi][ni] = (f32x4){0.f,0.f,0.f,0.f};

  const int nk = K / BK;
  auto stage = [&](int buf, int k0) {
    #pragma unroll
    for (int j = 0; j < SLA/4; ++j) {
      const int s = j*4 + w;
      const int gr = s*RPS + ri;
      glds16(A + (m0+gr)*(long)lda + k0 + ((si ^ (gr&MASK))*8), &As[buf][s*512]);
    }
    #pragma unroll
    for (int j = 0; j < (SLB+3)/4; ++j) {
      const int s = j*4 + w;
      if (s < SLB) {
        const int gr = s*RPS + ri;
        glds16(Bt + (long)(n0+gr)*K + k0 + ((si ^ (gr&MASK))*8), &Bs[buf][s*512]);
      }
    }
  };

  stage(0, 0);
  __syncthreads();
  for (int kt = 0; kt < nk; ++kt) {
    const int cur = kt & 1;
    if (kt + 1 < nk) stage(cur^1, (kt+1)*BK);
    #pragma unroll
    for (int ks = 0; ks < KS; ++ks) {
      bf16x8 af[4], bfr[3];
      #pragma unroll
      for (int mi=0;mi<4;++mi) {
        const int ar = wm*64 + mi*16 + lr;
        const int slot = (ks*4 + lk) ^ (ar & MASK);
        af[mi] = *(const bf16x8*)(&As[cur][ar*BK + slot*8]);
      }
      #pragma unroll
      for (int ni=0;ni<3;++ni) {
        const int br = wn*48 + ni*16 + lr;
        const int slot = (ks*4 + lk) ^ (br & MASK);
        bfr[ni] = *(const bf16x8*)(&Bs[cur][br*BK + slot*8]);
      }
      #pragma unroll
      for (int mi=0;mi<4;++mi)
        #pragma unroll
        for (int ni=0;ni<3;++ni)
          acc[mi][ni] = __builtin_amdgcn_mfma_f32_16x16x32_bf16(af[mi], bfr[ni], acc[mi][ni], 0, 0, 0);
    }
    __syncthreads();
  }

  #pragma unroll
  for (int mi=0;mi<4;++mi) {
    const long r0 = m0 + wm*64 + mi*16 + lk*4;
    #pragma unroll
    for (int ni=0;ni<3;++ni) {
      const int col = n0 + wn*48 + ni*16 + lr;
      const float bs = bias[col];
      #pragma unroll
      for (int e=0;e<4;++e) {
        const float v = acc[mi][ni][e] + bs;
        const long row = r0 + e;
        outb[row*ldo + ooff + col] = (EPI==1) ? (bf16_t)gelu_f(v) : (bf16_t)v;
      }
    }
  }
}

// ---------- GEMM-B: BM=64, BN=192 (full row), BK=64, fused resid+LN ----------
// EPI 0: resid RMW + LayerNorm -> xnout bf16
// EPI 1: resid RMW + bf16 copy -> xnout (no LN; final fc2)
template<int EPI>
__global__ __launch_bounds__(256) void gemmb_k(
    const bf16_t* __restrict__ A,
    const bf16_t* __restrict__ Bt,
    const float* __restrict__ bias,
    float* __restrict__ resid,
    bf16_t* __restrict__ xnout,
    const float* __restrict__ gg, const float* __restrict__ bb,
    int K) {
  constexpr int BK=64, MASK=7;
  __shared__ bf16_t As[2][64*64];    // 16KB
  __shared__ bf16_t Bs[2][192*64];   // 48KB
  const int tid = threadIdx.x;
  const int w = tid >> 6, l = tid & 63;
  const int lr = l & 15, lk = l >> 4;
  const int ri = l >> 3, si = l & 7;
  const long m0 = (long)blockIdx.x * 64;

  f32x4 acc[4][3];
  #pragma unroll
  for (int mi=0;mi<4;++mi)
    #pragma unroll
    for (int ni=0;ni<3;++ni) acc[mi][ni] = (f32x4){0.f,0.f,0.f,0.f};

  const int nk = K / BK;
  auto stage = [&](int buf, int k0) {
    #pragma unroll
    for (int j = 0; j < 2; ++j) {
      const int s = j*4 + w;
      const int gr = s*8 + ri;
      glds16(A + (m0+gr)*(long)K + k0 + ((si ^ (gr&MASK))*8), &As[buf][s*512]);
    }
    #pragma unroll
    for (int j = 0; j < 6; ++j) {
      const int s = j*4 + w;
      const int gr = s*8 + ri;
      glds16(Bt + (long)gr*K + k0 + ((si ^ (gr&MASK))*8), &Bs[buf][s*512]);
    }
  };

  stage(0, 0);
  __syncthreads();
  for (int kt = 0; kt < nk; ++kt) {
    const int cur = kt & 1;
    if (kt + 1 < nk) stage(cur^1, (kt+1)*BK);
    #pragma unroll
    for (int ks = 0; ks < 2; ++ks) {
      bf16x8 af[4], bfr[3];
      #pragma unroll
      for (int mi=0;mi<4;++mi) {
        const int ar = mi*16 + lr;
        const int slot = (ks*4 + lk) ^ (ar & MASK);
        af[mi] = *(const bf16x8*)(&As[cur][ar*64 + slot*8]);
      }
      #pragma unroll
      for (int ni=0;ni<3;++ni) {
        const int br = w*48 + ni*16 + lr;
        const int slot = (ks*4 + lk) ^ (br & MASK);
        bfr[ni] = *(const bf16x8*)(&Bs[cur][br*64 + slot*8]);
      }
      #pragma unroll
      for (int mi=0;mi<4;++mi)
        #pragma unroll
        for (int ni=0;ni<3;++ni)
          acc[mi][ni] = __builtin_amdgcn_mfma_f32_16x16x32_bf16(af[mi], bfr[ni], acc[mi][ni], 0, 0, 0);
    }
    __syncthreads();
  }

  // epilogue: v = acc + bias + resid ; resid = v
  #pragma unroll
  for (int mi=0;mi<4;++mi) {
    #pragma unroll
    for (int ni=0;ni<3;++ni) {
      const int col = w*48 + ni*16 + lr;
      const float bs = bias[col];
      #pragma unroll
      for (int e=0;e<4;++e) {
        const long row = m0 + mi*16 + lk*4 + e;
        float v = acc[mi][ni][e] + bs + resid[row*CCH + col];
        acc[mi][ni][e] = v;
        resid[row*CCH + col] = v;
        if (EPI == 1) xnout[row*CCH + col] = (bf16_t)v;
      }
    }
  }
  if (EPI == 0) {
    float* red  = (float*)&As[0][0];    // [64 rows][4 waves][2]
    float* stat = red + 512;            // [64 rows][2]
    #pragma unroll
    for (int mi=0;mi<4;++mi) {
      #pragma unroll
      for (int e=0;e<4;++e) {
        float p1 = acc[mi][0][e] + acc[mi][1][e] + acc[mi][2][e];
        float p2 = acc[mi][0][e]*acc[mi][0][e] + acc[mi][1][e]*acc[mi][1][e]
                 + acc[mi][2][e]*acc[mi][2][e];
        #pragma unroll
        for (int off=1; off<16; off<<=1) {
          p1 += __shfl_xor(p1, off);
          p2 += __shfl_xor(p2, off);
        }
        if (lr == 0) {
          const int r = mi*16 + lk*4 + e;
          red[(r*4 + w)*2]     = p1;
          red[(r*4 + w)*2 + 1] = p2;
        }
      }
    }
    __syncthreads();
    if (tid < 64) {
      const int r = tid;
      float s1 = red[(r*4+0)*2] + red[(r*4+1)*2] + red[(r*4+2)*2] + red[(r*4+3)*2];
      float s2 = red[(r*4+0)*2+1] + red[(r*4+1)*2+1] + red[(r*4+2)*2+1] + red[(r*4+3)*2+1];
      const float mu = s1 * (1.f/CCH);
      stat[r*2]   = mu;
      stat[r*2+1] = rsqrtf(s2*(1.f/CCH) - mu*mu + 1e-5f);
    }
    __syncthreads();
    #pragma unroll
    for (int mi=0;mi<4;++mi) {
      #pragma unroll
      for (int e=0;e<4;++e) {
        const int r = mi*16 + lk*4 + e;
        const float mu = stat[r*2], rstd = stat[r*2+1];
        #pragma unroll
        for (int ni=0;ni<3;++ni) {
          const int col = w*48 + ni*16 + lr;
          xnout[(m0+r)*CCH + col] = (bf16_t)((acc[mi][ni][e]-mu)*rstd*gg[col] + bb[col]);
        }
      }
    }
  }
}

// ---------- window attention (1 block = 1 window, 1 wave = 1 head) ----------
__global__ __launch_bounds__(256) void win_attn_k(
    const bf16_t* __restrict__ qkv, bf16_t* __restrict__ aout,
    const float* __restrict__ rpb, int shift) {
  __shared__ float Ks[4][64][24];
  __shared__ float Vs[4][64][24];
  const int h = threadIdx.x >> 6, l = threadIdx.x & 63;
  const int wblk = blockIdx.x;
  const int b = wblk / 576, wi = wblk % 576;
  const int wh = wi / 24, ww = wi % 24;
  const int r = l >> 3, c = l & 7;
  const int hr = wh*8 + r, wr = ww*8 + c;
  int ho = hr + shift; if (ho >= 192) ho -= 192;
  int wo = wr + shift; if (wo >= 192) wo -= 192;
  const long tok = (long)b*36864 + (long)ho*192 + wo;
  const bf16_t* base = qkv + tok*576 + h*24;
  float q[24];
  #pragma unroll
  for (int j=0; j<3; ++j) {
    bf16x8 qv8 = *(const bf16x8*)(base + j*8);
    bf16x8 kv8 = *(const bf16x8*)(base + 96 + j*8);
    bf16x8 vv8 = *(const bf16x8*)(base + 192 + j*8);
    #pragma unroll
    for (int e=0; e<8; ++e) {
      q[j*8+e] = (float)qv8[e];
      Ks[h][l][j*8+e] = (float)kv8[e];
      Vs[h][l][j*8+e] = (float)vv8[e];
    }
  }
  __syncthreads();
  int qid = 0;
  if (shift) {
    int hid = (hr < 184) ? 0 : (hr < 188 ? 1 : 2);
    int wid2 = (wr < 184) ? 0 : (wr < 188 ? 1 : 2);
    qid = hid*3 + wid2;
  }
  const float scale = 0.20412414523193154f;
  float lg[64];
  #pragma unroll
  for (int m=0; m<64; ++m) {
    int r2 = m >> 3, c2 = m & 7;
    float dot = 0.f;
    #pragma unroll
    for (int d4=0; d4<6; ++d4) {
      float4 kv = *(const float4*)(&Ks[h][m][d4*4]);
      dot += q[d4*4+0]*kv.x + q[d4*4+1]*kv.y + q[d4*4+2]*kv.z + q[d4*4+3]*kv.w;
    }
    int ridx = (r - r2 + 7)*15 + (c - c2 + 7);
    float v = dot*scale + rpb[ridx*4 + h];
    if (shift) {
      int hr2 = wh*8 + r2, wr2 = ww*8 + c2;
      int hid2 = (hr2 < 184) ? 0 : (hr2 < 188 ? 1 : 2);
      int wid3 = (wr2 < 184) ? 0 : (wr2 < 188 ? 1 : 2);
      if (hid2*3 + wid3 != qid) v -= 100.f;
    }
    lg[m] = v;
  }
  float mx = -1e30f;
  #pragma unroll
  for (int m=0; m<64; ++m) mx = fmaxf(mx, lg[m]);
  float s = 0.f;
  float o[24];
  #pragma unroll
  for (int d=0; d<24; ++d) o[d] = 0.f;
  #pragma unroll
  for (int m=0; m<64; ++m) {
    float p = __expf(lg[m] - mx);
    s += p;
    #pragma unroll
    for (int d4=0; d4<6; ++d4) {
      float4 vv = *(const float4*)(&Vs[h][m][d4*4]);
      o[d4*4+0] += p*vv.x; o[d4*4+1] += p*vv.y; o[d4*4+2] += p*vv.z; o[d4*4+3] += p*vv.w;
    }
  }
  float inv = 1.f/s;
  bf16_t* ob = aout + tok*192 + h*24;
  #pragma unroll
  for (int j=0; j<3; ++j) {
    bf16x8 ov;
    #pragma unroll
    for (int e=0; e<8; ++e) ov[e] = (bf16_t)(o[j*8+e]*inv);
    *(bf16x8*)(ob + j*8) = ov;
  }
}

// ---------- anchored stripe attention ----------
__global__ __launch_bounds__(256) void stripe_attn_k(
    const bf16_t* __restrict__ qkv, const bf16_t* __restrict__ xn,
    bf16_t* __restrict__ aout) {
  __shared__ float Ks[4][64][24];
  __shared__ float Vs[4][64][24];
  __shared__ float An[4][16][24];
  __shared__ float Ts[4][16][24];
  const int h = threadIdx.x >> 6, l = threadIdx.x & 63;
  const int wblk = blockIdx.x;
  const int b = wblk / 576, wi = wblk % 576;
  const int wh = wi / 24, ww = wi % 24;
  const int r = l >> 3, c = l & 7;
  const long tok = (long)b*36864 + (long)(wh*8+r)*192 + (ww*8+c);
  const bf16_t* base = qkv + tok*576 + 288 + h*24;
  #pragma unroll
  for (int j=0; j<3; ++j) {
    bf16x8 kv8 = *(const bf16x8*)(base + 96 + j*8);
    bf16x8 vv8 = *(const bf16x8*)(base + 192 + j*8);
    #pragma unroll
    for (int e=0; e<8; ++e) {
      Ks[h][l][j*8+e] = (float)kv8[e];
      Vs[h][l][j*8+e] = (float)vv8[e];
    }
  }
  {
    int m = l >> 2, dq = l & 3;
    int ar = m >> 2, ac = m & 3;
    const long trow = (long)b*36864 + (long)(wh*8 + 2*ar)*192 + (ww*8 + 2*ac);
    #pragma unroll
    for (int j=0; j<6; ++j) {
      int d = dq*6 + j;
      float ssum = 0.f;
      ssum += (float)xn[trow*192       + 96 + h*24 + d];
      ssum += (float)xn[(trow+1)*192   + 96 + h*24 + d];
      ssum += (float)xn[(trow+192)*192 + 96 + h*24 + d];
      ssum += (float)xn[(trow+193)*192 + 96 + h*24 + d];
      An[h][m][d] = 0.25f*ssum;
    }
  }
  __syncthreads();
  const float scale = 0.20412414523193154f;
  {
    int g = l >> 2, qq = l & 3;
    float l2[16];
    #pragma unroll
    for (int t=0; t<16; ++t) {
      int k = qq*16 + t;
      float dot = 0.f;
      #pragma unroll
      for (int d4=0; d4<6; ++d4) {
        float4 av = *(const float4*)(&An[h][g][d4*4]);
        float4 kv = *(const float4*)(&Ks[h][k][d4*4]);
        dot += av.x*kv.x + av.y*kv.y + av.z*kv.z + av.w*kv.w;
      }
      l2[t] = dot*scale;
    }
    float mx = -1e30f;
    #pragma unroll
    for (int t=0; t<16; ++t) mx = fmaxf(mx, l2[t]);
    mx = fmaxf(mx, __shfl_xor(mx, 1));
    mx = fmaxf(mx, __shfl_xor(mx, 2));
    float ssum = 0.f;
    float p[16];
    #pragma unroll
    for (int t=0; t<16; ++t) { p[t] = __expf(l2[t]-mx); ssum += p[t]; }
    ssum += __shfl_xor(ssum, 1);
    ssum += __shfl_xor(ssum, 2);
    float ta[24];
    #pragma unroll
    for (int d=0; d<24; ++d) ta[d] = 0.f;
    #pragma unroll
    for (int t=0; t<16; ++t) {
      int k = qq*16 + t;
      #pragma unroll
      for (int d4=0; d4<6; ++d4) {
        float4 vv = *(const float4*)(&Vs[h][k][d4*4]);
        ta[d4*4+0] += p[t]*vv.x; ta[d4*4+1] += p[t]*vv.y;
        ta[d4*4+2] += p[t]*vv.z; ta[d4*4+3] += p[t]*vv.w;
      }
    }
    #pragma unroll
    for (int d=0; d<24; ++d) {
      ta[d] += __shfl_xor(ta[d], 1);
      ta[d] += __shfl_xor(ta[d], 2);
    }
    float inv = 1.f/ssum;
    #pragma unroll
    for (int j=0; j<6; ++j) Ts[h][g][qq*6+j] = ta[qq*6+j]*inv;
  }
  __syncthreads();
  {
    float qv[24];
    #pragma unroll
    for (int j=0; j<3; ++j) {
      bf16x8 q8 = *(const bf16x8*)(base + j*8);
      #pragma unroll
      for (int e=0; e<8; ++e) qv[j*8+e] = (float)q8[e];
    }
    float lg[16];
    #pragma unroll
    for (int m=0; m<16; ++m) {
      float dot = 0.f;
      #pragma unroll
      for (int d4=0; d4<6; ++d4) {
        float4 av = *(const float4*)(&An[h][m][d4*4]);
        dot += qv[d4*4+0]*av.x + qv[d4*4+1]*av.y + qv[d4*4+2]*av.z + qv[d4*4+3]*av.w;
      }
      lg[m] = dot*scale;
    }
    float mx = -1e30f;
    #pragma unroll
    for (int m=0; m<16; ++m) mx = fmaxf(mx, lg[m]);
    float s = 0.f;
    float o[24];
    #pragma unroll
    for (int d=0; d<24; ++d) o[d] = 0.f;
    #pragma unroll
    for (int m=0; m<16; ++m) {
      float p = __expf(lg[m]-mx);
      s += p;
      #pragma unroll
      for (int d4=0; d4<6; ++d4) {
        float4 tv = *(const float4*)(&Ts[h][m][d4*4]);
        o[d4*4+0] += p*tv.x; o[d4*4+1] += p*tv.y; o[d4*4+2] += p*tv.z; o[d4*4+3] += p*tv.w;
      }
    }
    float inv = 1.f/s;
    bf16_t* ob = aout + tok*192 + 96 + h*24;
    #pragma unroll
    for (int j=0; j<3; ++j) {
      bf16x8 ov;
      #pragma unroll
      for (int e=0; e<8; ++e) ov[e] = (bf16_t)(o[j*8+e]*inv);
      *(bf16x8*)(ob + j*8) = ov;
    }
  }
}

// ---------- conv v3: block = 1 image row (192 tok) x 64 co ----------
__global__ __launch_bounds__(256) void conv3_k(
    const bf16_t* __restrict__ xb,   // [2][192][192][192] bf16
    const bf16_t* __restrict__ Wc,   // [9][192][192] bf16
    const float* __restrict__ cb,
    const float* __restrict__ res0,
    const bf16_t* __restrict__ zb,   // >=1KB of zeros
    float* __restrict__ out) {
  __shared__ bf16_t Xs[19968];   // [3 dy][208 tok][32 ch] = 39,936B
  __shared__ bf16_t Bs[18432];   // [9 tap][64 co][32 ch] = 36,864B
  const int tid = threadIdx.x;
  const int w = tid >> 6, l = tid & 63;
  const int lr = l & 15, lk = l >> 4;
  const int rq = l >> 2, cq = (l & 3) * 8;
  const int bx = blockIdx.x;
  const int bimg = bx / 192, h = bx % 192;
  const int co0 = blockIdx.y * 64;

  f32x4 acc[3][4];
  #pragma unroll
  for (int mi=0; mi<3; ++mi)
    #pragma unroll
    for (int ni=0; ni<4; ++ni) acc[mi][ni] = (f32x4){0.f,0.f,0.f,0.f};

  for (int kcs = 0; kcs < 6; ++kcs) {
    const int kc = kcs * 32;
    for (int j = 0; j < 10; ++j) {
      int s = j*4 + w;
      if (s < 39) {
        int dy = s / 13, rem = s - dy*13;
        int tokcol = rem*16 + rq;     // 0..207
        int wc = tokcol - 1;
        int hp = h + dy - 1;
        const bf16_t* src = zb + cq;
        if (hp >= 0 && hp < 192 && wc >= 0 && wc < 192)
          src = xb + ((long)bimg*36864 + (long)hp*192 + wc)*192 + kc + cq;
        glds16(src, &Xs[s*512]);
      }
    }
    for (int j = 0; j < 9; ++j) {
      int s = j*4 + w;
      int tap = s >> 2, rem = s & 3;
      int row = rem*16 + rq;
      glds16(Wc + ((long)(tap*192 + co0 + row))*192 + kc + cq, &Bs[s*512]);
    }
    __syncthreads();
    #pragma unroll
    for (int tap = 0; tap < 9; ++tap) {
      const int dy = tap/3, dx = tap%3 - 1;
      bf16x8 af[3];
      #pragma unroll
      for (int mi=0; mi<3; ++mi) {
        int tokcol = w*48 + mi*16 + lr + dx + 1;
        af[mi] = *(const bf16x8*)(&Xs[dy*6656 + tokcol*32 + lk*8]);
      }
      #pragma unroll
      for (int ni=0; ni<4; ++ni) {
        bf16x8 bfr = *(const bf16x8*)(&Bs[tap*2048 + (ni*16+lr)*32 + lk*8]);
        #pragma unroll
        for (int mi=0; mi<3; ++mi)
          acc[mi][ni] = __builtin_amdgcn_mfma_f32_16x16x32_bf16(af[mi], bfr, acc[mi][ni], 0, 0, 0);
      }
    }
    if (kcs < 5) __syncthreads();
  }

  #pragma unroll
  for (int mi=0; mi<3; ++mi) {
    #pragma unroll
    for (int ni=0; ni<4; ++ni) {
      const int col = co0 + ni*16 + lr;
      const float cbv = cb[col];
      #pragma unroll
      for (int e=0; e<4; ++e) {
        const int tl = w*48 + mi*16 + lk*4 + e;
        const long tok = (long)bimg*36864 + (long)h*192 + tl;
        out[tok*192 + col] = acc[mi][ni][e] + cbv + res0[tok*192 + col];
      }
    }
  }
}

extern "C" void kernel_launch(void* const* d_in, const int* in_sizes, int n_in,
                              void* d_out, int out_size, void* d_ws, size_t ws_size,
                              hipStream_t stream) {
  const float* x_in     = (const float*)d_in[0];
  const float* norm1_g  = (const float*)d_in[1];
  const float* norm1_b  = (const float*)d_in[2];
  const float* qkv_w_w  = (const float*)d_in[3];
  const float* qkv_b_w  = (const float*)d_in[4];
  const float* qkv_w_s  = (const float*)d_in[5];
  const float* qkv_b_s  = (const float*)d_in[6];
  const float* proj_w   = (const float*)d_in[7];
  const float* proj_b   = (const float*)d_in[8];
  const float* rpb      = (const float*)d_in[9];
  const float* norm2_g  = (const float*)d_in[10];
  const float* norm2_b  = (const float*)d_in[11];
  const float* fc1_w    = (const float*)d_in[12];
  const float* fc1_b    = (const float*)d_in[13];
  const float* fc2_w    = (const float*)d_in[14];
  const float* fc2_b    = (const float*)d_in[15];
  const float* conv_w   = (const float*)d_in[16];
  const float* conv_b   = (const float*)d_in[17];

  char* ws = (char*)d_ws;
  float*  x_cur = (float*)ws;                         // 56,623,104 B
  bf16_t* xn    = (bf16_t*)(ws + 56623104);           // 28,311,552 B
  bf16_t* qh    = (bf16_t*)(ws + 84934656);           // 113,246,208 B
  bf16_t* aoutb = (bf16_t*)(ws + 198180864);          // 28,311,552 B (also final-x bf16)
  bf16_t* WwinT = (bf16_t*)(ws + 226492416);
  bf16_t* WstrT  = WwinT  + 110592;
  bf16_t* WprojT = WstrT  + 110592;
  bf16_t* Wfc1T  = WprojT + 147456;
  bf16_t* Wfc2T  = Wfc1T  + 589824;
  bf16_t* WconvT = Wfc2T  + 589824;

  wprep_k<<<(4*96*288 + 255)/256, 256, 0, stream>>>(qkv_w_w, WwinT, 96, 288, 4L*96*288);
  wprep_k<<<(4*96*288 + 255)/256, 256, 0, stream>>>(qkv_w_s, WstrT, 96, 288, 4L*96*288);
  wprep_k<<<(4*192*192 + 255)/256, 256, 0, stream>>>(proj_w, WprojT, 192, 192, 4L*192*192);
  wprep_k<<<(4*192*768 + 255)/256, 256, 0, stream>>>(fc1_w, Wfc1T, 192, 768, 4L*192*768);
  wprep_k<<<(4*768*192 + 255)/256, 256, 0, stream>>>(fc2_w, Wfc2T, 768, 192, 4L*768*192);
  cprep_k<<<(9*192*192 + 255)/256, 256, 0, stream>>>(conv_w, WconvT);

  // LN of layer 0 + copy x -> x_cur
  ln0_k<<<TOKS/4, 256, 0, stream>>>(x_in, norm1_g, norm1_b, xn, x_cur);

  const int MB = TOKS/128;   // 576
  const int MB2 = TOKS/64;   // 1152
  for (int i = 0; i < 4; ++i) {
    int shift = (i % 2 == 0) ? 4 : 0;
    dim3 g3(MB, 3), g8(MB, 8);
    gemma_k<32,0><<<g3, 256, 0, stream>>>(xn,      192, WwinT + (long)i*27648, qkv_b_w + i*288,
                                          qh, 576, 0,   96);
    gemma_k<32,0><<<g3, 256, 0, stream>>>(xn + 96, 192, WstrT + (long)i*27648, qkv_b_s + i*288,
                                          qh, 576, 288, 96);
    win_attn_k<<<1152, 256, 0, stream>>>(qh, aoutb, rpb + i*900, shift);
    stripe_attn_k<<<1152, 256, 0, stream>>>(qh, xn, aoutb);
    // proj + resid RMW + LN2 -> xn
    gemmb_k<0><<<MB2, 256, 0, stream>>>(aoutb, WprojT + (long)i*36864, proj_b + i*192,
                                        x_cur, xn, norm2_g + i*192, norm2_b + i*192, 192);
    gemma_k<64,1><<<g8, 256, 0, stream>>>(xn, 192, Wfc1T + (long)i*147456, fc1_b + i*768,
                                          qh, 768, 0, 192);
    if (i < 3)
      gemmb_k<0><<<MB2, 256, 0, stream>>>(qh, Wfc2T + (long)i*147456, fc2_b + i*192,
                                          x_cur, xn, norm1_g + (i+1)*192, norm1_b + (i+1)*192, 768);
    else
      gemmb_k<1><<<MB2, 256, 0, stream>>>(qh, Wfc2T + (long)i*147456, fc2_b + i*192,
                                          x_cur, aoutb, nullptr, nullptr, 768);
  }
  // zero scratch for conv padding reads (qh is free now)
  hipMemsetAsync(qh, 0, 4096, stream);
  dim3 gc(384, 3);
  conv3_k<<<gc, 256, 0, stream>>>(aoutb, WconvT, conv_b, x_in, qh, (float*)d_out);
}